// Round 1
// baseline (18217.825 us; speedup 1.0000x reference)
//
#include <hip/hip_runtime.h>
#include <cstddef>

#define H2 128
#define W2 128
#define NPIX (H2 * W2)
#define B_ 2
#define T_ 6
#define L_ 13
#define PB 8

__device__ __forceinline__ float leakyf(float x) { return x >= 0.0f ? x : 0.2f * x; }
__device__ __forceinline__ float sigmf(float x) { return 1.0f / (1.0f + expf(-x)); }

// ---------------- stem: 3x3 stride-2 pad-1 conv, (B,6,256,256) -> (B,384,128,128), leaky ----------------
__global__ void stem_kernel(const float* __restrict__ x, const float* __restrict__ w,
                            const float* __restrict__ bias, float* __restrict__ ys) {
    int idx = blockIdx.x * 256 + threadIdx.x;
    int p  = idx % NPIX;
    int oc = (idx / NPIX) % 384;
    int b  = idx / (NPIX * 384);
    int oy = p / W2, ox = p % W2;
    float acc = bias[oc];
    const float* wb = w + (size_t)oc * 54;
    #pragma unroll
    for (int ic = 0; ic < 6; ++ic) {
        const float* xb = x + ((size_t)b * 6 + ic) * 65536;
        #pragma unroll
        for (int ky = 0; ky < 3; ++ky) {
            int iy = oy * 2 - 1 + ky;
            if ((unsigned)iy >= 256u) continue;
            #pragma unroll
            for (int kx = 0; kx < 3; ++kx) {
                int ix = ox * 2 - 1 + kx;
                if ((unsigned)ix >= 256u) continue;
                acc += xb[iy * 256 + ix] * wb[(ic * 3 + ky) * 3 + kx];
            }
        }
    }
    ys[idx] = leakyf(acc);
}

// ---------------- i2h: 3x3 pad-1 conv, 64 -> 192 (no activation) ----------------
__global__ void i2h_kernel(const float* __restrict__ ys, int t,
                           const float* __restrict__ w, const float* __restrict__ bias,
                           float* __restrict__ o) {
    int idx = blockIdx.x * 256 + threadIdx.x;
    int p  = idx % NPIX;
    int oc = (idx / NPIX) % 192;
    int b  = idx / (NPIX * 192);
    int oy = p / W2, ox = p % W2;
    const float* xb = ys + ((size_t)b * 384 + t * 64) * NPIX;
    const float* wb = w + (size_t)oc * 576;
    float acc = bias[oc];
    for (int c = 0; c < 64; ++c) {
        const float* xc = xb + c * NPIX;
        const float* wc = wb + c * 9;
        #pragma unroll
        for (int ky = 0; ky < 3; ++ky) {
            int iy = oy - 1 + ky;
            if ((unsigned)iy >= (unsigned)H2) continue;
            #pragma unroll
            for (int kx = 0; kx < 3; ++kx) {
                int ix = ox - 1 + kx;
                if ((unsigned)ix >= (unsigned)W2) continue;
                acc += xc[iy * W2 + ix] * wc[ky * 3 + kx];
            }
        }
    }
    o[idx] = acc;
}

// ---------------- f1 = leaky(i2f(xt) + h2f(hprev)): two 5x5 pad-2 convs 64 -> 32 ----------------
__global__ void f1_kernel(const float* __restrict__ ys, int t,
                          const float* __restrict__ hprev, int hstride_b,
                          const float* __restrict__ wi, const float* __restrict__ bi,
                          const float* __restrict__ wh, const float* __restrict__ bh,
                          float* __restrict__ f1) {
    int idx = blockIdx.x * 256 + threadIdx.x;
    int p = idx % NPIX;
    int j = (idx / NPIX) % 32;
    int b = idx / (NPIX * 32);
    int oy = p / W2, ox = p % W2;
    const float* xb  = ys + ((size_t)b * 384 + t * 64) * NPIX;
    const float* hb  = hprev + (size_t)b * hstride_b;
    const float* wib = wi + (size_t)j * 1600;
    const float* whb = wh + (size_t)j * 1600;
    float acc = bi[j] + bh[j];
    for (int c = 0; c < 64; ++c) {
        const float* xc = xb + c * NPIX;
        const float* hc = hb + c * NPIX;
        #pragma unroll
        for (int ky = 0; ky < 5; ++ky) {
            int iy = oy - 2 + ky;
            if ((unsigned)iy >= (unsigned)H2) continue;
            #pragma unroll
            for (int kx = 0; kx < 5; ++kx) {
                int ix = ox - 2 + kx;
                if ((unsigned)ix >= (unsigned)W2) continue;
                int off  = iy * W2 + ix;
                int woff = (c * 5 + ky) * 5 + kx;
                acc += xc[off] * wib[woff] + hc[off] * whb[woff];
            }
        }
    }
    f1[idx] = leakyf(acc);
}

// ---------------- flow: 5x5 pad-2 conv, 32 -> 26 (no activation) ----------------
__global__ void flow_kernel(const float* __restrict__ f1,
                            const float* __restrict__ w, const float* __restrict__ bias,
                            float* __restrict__ flows) {
    int idx = blockIdx.x * 256 + threadIdx.x;
    int p  = idx % NPIX;
    int fc = (idx / NPIX) % 26;
    int b  = idx / (NPIX * 26);
    int oy = p / W2, ox = p % W2;
    const float* fb = f1 + (size_t)b * 32 * NPIX;
    const float* wb = w + (size_t)fc * 800;
    float acc = bias[fc];
    for (int c = 0; c < 32; ++c) {
        const float* fc2 = fb + c * NPIX;
        const float* wc  = wb + c * 25;
        #pragma unroll
        for (int ky = 0; ky < 5; ++ky) {
            int iy = oy - 2 + ky;
            if ((unsigned)iy >= (unsigned)H2) continue;
            #pragma unroll
            for (int kx = 0; kx < 5; ++kx) {
                int ix = ox - 2 + kx;
                if ((unsigned)ix >= (unsigned)W2) continue;
                acc += fc2[iy * W2 + ix] * wc[ky * 5 + kx];
            }
        }
    }
    flows[idx] = acc;
}

// ---------------- fused: bilinear warp (13 flows) + 1x1 conv 832->192 + GRU gates ----------------
__global__ __launch_bounds__(256) void warpret_kernel(
    const float* __restrict__ hprev, int hstride_b,
    const float* __restrict__ flows,
    const float* __restrict__ w_ret, const float* __restrict__ b_ret,
    const float* __restrict__ i2h, float* __restrict__ out, int t) {
    __shared__ float s_warp[832 * PB];   // 26.6 KB, layout [m=l*64+c][p]
    __shared__ float s_h2h[192 * PB];    // 6 KB
    __shared__ int   s_x0[L_ * PB];
    __shared__ int   s_y0[L_ * PB];
    __shared__ float s_wx1[L_ * PB];
    __shared__ float s_wy1[L_ * PB];

    int tid  = threadIdx.x;
    int g0   = blockIdx.x * PB;          // 8 consecutive pixels, never spans batch
    int b    = g0 / NPIX;
    int pix0 = g0 % NPIX;
    const float* hb = hprev + (size_t)b * hstride_b;

    // phase 0: flow -> sample coords per (l, p)
    if (tid < L_ * PB) {
        int l = tid / PB, p = tid % PB;
        int pix = pix0 + p;
        int py = pix / W2, px = pix % W2;
        float u = flows[((size_t)b * 26 + l * 2) * NPIX + pix];
        float v = flows[((size_t)b * 26 + l * 2 + 1) * NPIX + pix];
        float sx = (float)px - u;
        float sy = (float)py - v;
        float x0f = floorf(sx), y0f = floorf(sy);
        s_x0[tid]  = (int)x0f;
        s_y0[tid]  = (int)y0f;
        s_wx1[tid] = sx - x0f;
        s_wy1[tid] = sy - y0f;
    }
    __syncthreads();

    // phase 1: warped[l*64+c][p] via 4-corner gather
    for (int idx = tid; idx < 832 * PB; idx += 256) {
        int l   = idx / (64 * PB);
        int rem = idx - l * (64 * PB);
        int c = rem / PB, p = rem % PB;
        int q = l * PB + p;
        int x0 = s_x0[q], y0 = s_y0[q];
        float wx1 = s_wx1[q], wy1 = s_wy1[q];
        float wx0 = 1.0f - wx1, wy0 = 1.0f - wy1;
        const float* hc = hb + (size_t)c * NPIX;
        bool vx0 = (unsigned)x0 < (unsigned)W2;
        bool vx1 = (unsigned)(x0 + 1) < (unsigned)W2;
        bool vy0 = (unsigned)y0 < (unsigned)H2;
        bool vy1 = (unsigned)(y0 + 1) < (unsigned)H2;
        float v00 = (vx0 && vy0) ? hc[y0 * W2 + x0] : 0.0f;
        float v10 = (vx1 && vy0) ? hc[y0 * W2 + x0 + 1] : 0.0f;
        float v01 = (vx0 && vy1) ? hc[(y0 + 1) * W2 + x0] : 0.0f;
        float v11 = (vx1 && vy1) ? hc[(y0 + 1) * W2 + x0 + 1] : 0.0f;
        s_warp[idx] = (v00 * wx0 + v10 * wx1) * wy0 + (v01 * wx0 + v11 * wx1) * wy1;
    }
    __syncthreads();

    // phase 2: h2h[o][p] = b_ret[o] + sum_m w_ret[o][m] * warped[m][p]
    #pragma unroll
    for (int k = 0; k < (192 * PB) / 256; ++k) {
        int idx = k * 256 + tid;
        int oc = idx / PB, p = idx % PB;
        const float* wr = w_ret + (size_t)oc * 832;
        float acc = b_ret[oc];
        for (int m2 = 0; m2 < 832; ++m2)
            acc += wr[m2] * s_warp[m2 * PB + p];
        s_h2h[idx] = acc;
    }
    __syncthreads();

    // phase 3: GRU gates -> hnext, written straight into out[b][t]
    for (int idx = tid; idx < 64 * PB; idx += 256) {
        int c = idx / PB, p = idx % PB;
        int pix = pix0 + p;
        const float* ib = i2h + (size_t)b * 192 * NPIX + pix;
        float ir = ib[(size_t)c * NPIX];
        float iu = ib[(size_t)(64 + c) * NPIX];
        float im = ib[(size_t)(128 + c) * NPIX];
        float hr = s_h2h[c * PB + p];
        float hu = s_h2h[(64 + c) * PB + p];
        float hm = s_h2h[(128 + c) * PB + p];
        float r = sigmf(ir + hr);
        float z = sigmf(iu + hu);
        float m = leakyf(im + r * hm);
        float hp = hb[(size_t)c * NPIX + pix];
        float hn = z * hp + (1.0f - z) * m;
        out[(((size_t)b * T_ + t) * 64 + c) * NPIX + pix] = hn;
    }
}

extern "C" void kernel_launch(void* const* d_in, const int* in_sizes, int n_in,
                              void* d_out, int out_size, void* d_ws, size_t ws_size,
                              hipStream_t stream) {
    const float* x      = (const float*)d_in[0];
    const float* w_stem = (const float*)d_in[1];
    const float* b_stem = (const float*)d_in[2];
    const float* w_i2h  = (const float*)d_in[3];
    const float* b_i2h  = (const float*)d_in[4];
    const float* w_i2f  = (const float*)d_in[5];
    const float* b_i2f  = (const float*)d_in[6];
    const float* w_h2f  = (const float*)d_in[7];
    const float* b_h2f  = (const float*)d_in[8];
    const float* w_flow = (const float*)d_in[9];
    const float* b_flow = (const float*)d_in[10];
    const float* w_ret  = (const float*)d_in[11];
    const float* b_ret  = (const float*)d_in[12];
    float* out = (float*)d_out;

    float* ws    = (float*)d_ws;
    float* ys    = ws;                                   // 2*384*NPIX = 12,582,912 f
    float* h0    = ys    + (size_t)2 * 384 * NPIX;       // 2*64*NPIX  =  2,097,152 f
    float* i2h   = h0    + (size_t)2 * 64  * NPIX;       // 2*192*NPIX =  6,291,456 f
    float* f1    = i2h   + (size_t)2 * 192 * NPIX;       // 2*32*NPIX  =  1,048,576 f
    float* flows = f1    + (size_t)2 * 32  * NPIX;       // 2*26*NPIX  =    851,968 f
    // total ws use: ~91.5 MB

    hipMemsetAsync(h0, 0, (size_t)2 * 64 * NPIX * sizeof(float), stream);

    stem_kernel<<<(2 * 384 * NPIX) / 256, 256, 0, stream>>>(x, w_stem, b_stem, ys);

    for (int t = 0; t < T_; ++t) {
        const float* hprev = (t == 0) ? h0 : out + (size_t)(t - 1) * 64 * NPIX;
        int hstride = (t == 0) ? 64 * NPIX : T_ * 64 * NPIX;
        i2h_kernel<<<(2 * 192 * NPIX) / 256, 256, 0, stream>>>(ys, t, w_i2h, b_i2h, i2h);
        f1_kernel<<<(2 * 32 * NPIX) / 256, 256, 0, stream>>>(ys, t, hprev, hstride,
                                                             w_i2f, b_i2f, w_h2f, b_h2f, f1);
        flow_kernel<<<(2 * 26 * NPIX) / 256, 256, 0, stream>>>(f1, w_flow, b_flow, flows);
        warpret_kernel<<<(2 * NPIX) / PB, 256, 0, stream>>>(hprev, hstride, flows,
                                                            w_ret, b_ret, i2h, out, t);
    }
}

// Round 2
// 2720.501 us; speedup vs baseline: 6.6965x; 6.6965x over previous
//
#include <hip/hip_runtime.h>
#include <cstddef>

#define NPIX 16384
#define T_ 6
#define L_ 13

typedef __attribute__((ext_vector_type(8))) short bf16x8;
typedef __attribute__((ext_vector_type(4))) float f32x4;

__device__ __forceinline__ float leakyf(float x){ return x >= 0.f ? x : 0.2f*x; }
__device__ __forceinline__ float sigmf(float x){ return 1.f/(1.f+__expf(-x)); }

__device__ __forceinline__ short f2bf(float f){
    unsigned u = __float_as_uint(f);
    u += 0x7fffu + ((u>>16)&1u);          // round-to-nearest-even
    return (short)(u>>16);
}

__device__ __forceinline__ f32x4 MFMA(bf16x8 a, bf16x8 b, f32x4 c){
    return __builtin_amdgcn_mfma_f32_16x16x32_bf16(a, b, c, 0, 0, 0);
}

// ---------------- stem: 3x3 s2 p1 conv (B,6,256,256)->(B,384,128,128), leaky; 8 oc/thread ----------------
__global__ __launch_bounds__(256) void stem_kernel(const float* __restrict__ x,
        const float* __restrict__ w, const float* __restrict__ bias, float* __restrict__ ys){
    int idx = blockIdx.x*256 + threadIdx.x;
    int pix = idx & 16383;
    int r   = idx >> 14;
    int ocg = r % 48, b = r / 48;
    int oy = pix >> 7, ox = pix & 127;
    int oc0 = ocg*8;
    float xv[54];
    #pragma unroll
    for(int ic=0;ic<6;++ic)
      #pragma unroll
      for(int ky=0;ky<3;++ky){
        int iy = oy*2 - 1 + ky;
        #pragma unroll
        for(int kx=0;kx<3;++kx){
            int ix = ox*2 - 1 + kx;
            bool ok = (unsigned)iy<256u && (unsigned)ix<256u;
            xv[ic*9+ky*3+kx] = ok ? x[((size_t)b*6+ic)*65536 + iy*256 + ix] : 0.f;
        }
      }
    #pragma unroll
    for(int j=0;j<8;++j){
        int oc = oc0 + j;
        float a = bias[oc];
        const float* wb = w + (size_t)oc*54;
        #pragma unroll
        for(int tap=0;tap<54;++tap) a += xv[tap]*wb[tap];
        ys[((size_t)b*384 + oc)*NPIX + pix] = leakyf(a);
    }
}

// ---------------- i2h: 3x3 p1, 64->192, MFMA implicit GEMM. tile 64px x 64oc ----------------
__global__ __launch_bounds__(256) void i2h_mfma(const float* __restrict__ ys, int t,
        const float* __restrict__ w, const float* __restrict__ bias, float* __restrict__ o){
    __shared__ short xt[100*32];      // [halo pix 10x10][32 c]
    __shared__ short wt[576*32];      // [kk*64+oc][32 c]
    int bx = blockIdx.x;
    int ocg = bx % 3; int tile = (bx/3) % 256; int b = bx / 768;
    int ocb = ocg*64;
    int ty0 = (tile>>4)*8, tx0 = (tile&15)*8;
    int tid = threadIdx.x;
    int wid = tid>>6, lane = tid&63, lr = lane&15, lg = lane>>4;
    int mw = wid>>1, nw = wid&1;
    f32x4 acc[2][2] = {};
    const float* xbase = ys + ((size_t)b*384 + t*64)*NPIX;
    for(int cg=0; cg<2; ++cg){
        int cb = cg*32;
        __syncthreads();
        for(int i=tid; i<400; i+=256){               // stage x halo
            int pix = i>>2, ch = i&3;
            int hy = pix/10, hx = pix - hy*10;
            int py = ty0 - 1 + hy, px = tx0 - 1 + hx;
            bool ok = (unsigned)py < 128u && (unsigned)px < 128u;
            const float* src = xbase + (size_t)(cb + ch*8)*NPIX + py*128 + px;
            bf16x8 v;
            #pragma unroll
            for(int e=0;e<8;++e) v[e] = ok ? f2bf(src[(size_t)e*NPIX]) : (short)0;
            *(bf16x8*)&xt[pix*32 + ch*8] = v;
        }
        for(int i=tid; i<2304; i+=256){              // stage weights (all 9 taps)
            int r = i>>2, ch = i&3;
            int kk = r>>6, oc = r&63;
            const float* src = w + ((size_t)(ocb+oc)*64 + cb + ch*8)*9 + kk;
            bf16x8 v;
            #pragma unroll
            for(int e=0;e<8;++e) v[e] = f2bf(src[(size_t)e*9]);
            *(bf16x8*)&wt[r*32 + ch*8] = v;
        }
        __syncthreads();
        #pragma unroll
        for(int kk=0; kk<9; ++kk){
            int ky = kk/3, kx = kk%3;
            bf16x8 a[2], bb[2];
            #pragma unroll
            for(int mi=0;mi<2;++mi){
                int m = mw*32 + mi*16 + lr;
                int hp = ((m>>3)+ky)*10 + (m&7) + kx;
                a[mi] = *(const bf16x8*)&xt[hp*32 + lg*8];
            }
            #pragma unroll
            for(int ni=0;ni<2;++ni){
                int rr = kk*64 + nw*32 + ni*16 + lr;
                bb[ni] = *(const bf16x8*)&wt[rr*32 + lg*8];
            }
            #pragma unroll
            for(int mi=0;mi<2;++mi)
              #pragma unroll
              for(int ni=0;ni<2;++ni)
                acc[mi][ni] = MFMA(a[mi], bb[ni], acc[mi][ni]);
        }
    }
    #pragma unroll
    for(int mi=0;mi<2;++mi){
        int m0 = mw*32 + mi*16 + lg*4;
        int py = ty0 + (m0>>3), px = tx0 + (m0&7);
        #pragma unroll
        for(int ni=0;ni<2;++ni){
            int oc = ocb + nw*32 + ni*16 + lr;
            float bv = bias[oc];
            f32x4 r = acc[mi][ni];
            f32x4 st; st[0]=r[0]+bv; st[1]=r[1]+bv; st[2]=r[2]+bv; st[3]=r[3]+bv;
            *(f32x4*)&o[((size_t)b*192 + oc)*NPIX + py*128 + px] = st;
        }
    }
}

// ---------------- f1 = leaky(i2f(x) + h2f(h)): dual 5x5 p2, 64->32, MFMA. tile 64px x 32oc ----------------
__global__ __launch_bounds__(256) void f1_mfma(const float* __restrict__ ys, int t,
        const float* __restrict__ hprev, int hstride,
        const float* __restrict__ wi, const float* __restrict__ bi,
        const float* __restrict__ wh, const float* __restrict__ bh,
        float* __restrict__ f1){
    __shared__ short xt[144*32];      // [halo 12x12][32 c]
    __shared__ short wt[160*32];      // [kx*32+oc][32 c]
    int bx = blockIdx.x;
    int tile = bx & 255, b = bx>>8;
    int ty0 = (tile>>4)*8, tx0 = (tile&15)*8;
    int tid = threadIdx.x, wid = tid>>6, lane = tid&63, lr = lane&15, lg = lane>>4;
    int mw = wid>>1, nw = wid&1;
    f32x4 acc[2] = {};
    for(int inp=0; inp<2; ++inp){
        const float* xb = inp ? hprev + (size_t)b*hstride : ys + ((size_t)b*384 + t*64)*NPIX;
        const float* wsrc = inp ? wh : wi;
        for(int cg=0; cg<2; ++cg){
            int cb = cg*32;
            __syncthreads();
            for(int i=tid; i<576; i+=256){
                int pix=i>>2, ch=i&3;
                int hy = pix/12, hx = pix - hy*12;
                int py = ty0-2+hy, px = tx0-2+hx;
                bool ok = (unsigned)py<128u && (unsigned)px<128u;
                const float* src = xb + (size_t)(cb+ch*8)*NPIX + py*128+px;
                bf16x8 v;
                #pragma unroll
                for(int e=0;e<8;++e) v[e] = ok ? f2bf(src[(size_t)e*NPIX]) : (short)0;
                *(bf16x8*)&xt[pix*32+ch*8] = v;
            }
            for(int ky=0; ky<5; ++ky){
                __syncthreads();
                for(int i=tid; i<640; i+=256){
                    int r=i>>2, ch=i&3;
                    int kx = r>>5, oc = r&31;
                    const float* src = wsrc + ((size_t)oc*64 + cb + ch*8)*25 + ky*5 + kx;
                    bf16x8 v;
                    #pragma unroll
                    for(int e=0;e<8;++e) v[e] = f2bf(src[(size_t)e*25]);
                    *(bf16x8*)&wt[r*32+ch*8] = v;
                }
                __syncthreads();
                #pragma unroll
                for(int kx=0;kx<5;++kx){
                    bf16x8 a[2];
                    #pragma unroll
                    for(int mi=0;mi<2;++mi){
                        int m = mw*32+mi*16+lr;
                        int hp = ((m>>3)+ky)*12 + (m&7) + kx;
                        a[mi] = *(const bf16x8*)&xt[hp*32+lg*8];
                    }
                    bf16x8 bb = *(const bf16x8*)&wt[(kx*32 + nw*16 + lr)*32 + lg*8];
                    #pragma unroll
                    for(int mi=0;mi<2;++mi) acc[mi] = MFMA(a[mi], bb, acc[mi]);
                }
            }
        }
    }
    int j = nw*16 + lr;
    float bv = bi[j] + bh[j];
    #pragma unroll
    for(int mi=0;mi<2;++mi){
        int m0 = mw*32+mi*16+lg*4;
        int py = ty0 + (m0>>3), px = tx0 + (m0&7);
        f32x4 r = acc[mi];
        f32x4 st; st[0]=leakyf(r[0]+bv); st[1]=leakyf(r[1]+bv); st[2]=leakyf(r[2]+bv); st[3]=leakyf(r[3]+bv);
        *(f32x4*)&f1[((size_t)b*32 + j)*NPIX + py*128 + px] = st;
    }
}

// ---------------- flow: 5x5 p2, 32->26 (padded to 32), MFMA ----------------
__global__ __launch_bounds__(256) void flow_mfma(const float* __restrict__ f1,
        const float* __restrict__ w, const float* __restrict__ bias, float* __restrict__ flows){
    __shared__ short xt[144*32];
    __shared__ short wt[160*32];
    int bx = blockIdx.x;
    int tile = bx & 255, b = bx>>8;
    int ty0 = (tile>>4)*8, tx0 = (tile&15)*8;
    int tid = threadIdx.x, wid = tid>>6, lane = tid&63, lr = lane&15, lg = lane>>4;
    int mw = wid>>1, nw = wid&1;
    f32x4 acc[2] = {};
    const float* xb = f1 + (size_t)b*32*NPIX;
    __syncthreads();
    for(int i=tid; i<576; i+=256){
        int pix=i>>2, ch=i&3;
        int hy = pix/12, hx = pix - hy*12;
        int py = ty0-2+hy, px = tx0-2+hx;
        bool ok = (unsigned)py<128u && (unsigned)px<128u;
        const float* src = xb + (size_t)(ch*8)*NPIX + py*128+px;
        bf16x8 v;
        #pragma unroll
        for(int e=0;e<8;++e) v[e] = ok ? f2bf(src[(size_t)e*NPIX]) : (short)0;
        *(bf16x8*)&xt[pix*32+ch*8] = v;
    }
    for(int ky=0; ky<5; ++ky){
        __syncthreads();
        for(int i=tid; i<640; i+=256){
            int r=i>>2, ch=i&3;
            int kx = r>>5, oc = r&31;
            bf16x8 v;
            if(oc < 26){
                const float* src = w + ((size_t)oc*32 + ch*8)*25 + ky*5 + kx;
                #pragma unroll
                for(int e=0;e<8;++e) v[e] = f2bf(src[(size_t)e*25]);
            } else {
                #pragma unroll
                for(int e=0;e<8;++e) v[e] = (short)0;
            }
            *(bf16x8*)&wt[r*32+ch*8] = v;
        }
        __syncthreads();
        #pragma unroll
        for(int kx=0;kx<5;++kx){
            bf16x8 a[2];
            #pragma unroll
            for(int mi=0;mi<2;++mi){
                int m = mw*32+mi*16+lr;
                int hp = ((m>>3)+ky)*12 + (m&7) + kx;
                a[mi] = *(const bf16x8*)&xt[hp*32+lg*8];
            }
            bf16x8 bb = *(const bf16x8*)&wt[(kx*32 + nw*16 + lr)*32 + lg*8];
            #pragma unroll
            for(int mi=0;mi<2;++mi) acc[mi] = MFMA(a[mi], bb, acc[mi]);
        }
    }
    int j = nw*16 + lr;
    if(j < 26){
        float bv = bias[j];
        #pragma unroll
        for(int mi=0;mi<2;++mi){
            int m0 = mw*32+mi*16+lg*4;
            int py = ty0 + (m0>>3), px = tx0 + (m0&7);
            f32x4 r = acc[mi];
            f32x4 st; st[0]=r[0]+bv; st[1]=r[1]+bv; st[2]=r[2]+bv; st[3]=r[3]+bv;
            *(f32x4*)&flows[((size_t)b*26 + j)*NPIX + py*128 + px] = st;
        }
    }
}

// ---------------- warpret: warp-gather + (64px x 192oc x 832) MFMA GEMM + in-register GRU ----------------
__global__ __launch_bounds__(256) void warpret_mfma(
        const float* __restrict__ hprev, int hstride,
        const float* __restrict__ flows,
        const float* __restrict__ w_ret, const float* __restrict__ b_ret,
        const float* __restrict__ i2h, float* __restrict__ out, int t){
    __shared__ float s_sx[13*64], s_sy[13*64];
    __shared__ short At[64*32];       // warped slice [px][32 k]
    __shared__ short Bt[192*32];      // w_ret slice [oc][32 k]
    int bx = blockIdx.x;
    int half = bx & 1, row = (bx>>1) & 127, b = bx >> 8;
    int pxbase = half*64;
    int tid = threadIdx.x, wid = tid>>6, lane = tid&63, lr = lane&15, lg = lane>>4;
    const float* hb = hprev + (size_t)b*hstride;
    f32x4 acc[12] = {};
    for(int i=tid; i<13*64; i+=256){
        int l = i>>6, px = i&63;
        float u = flows[((size_t)b*26 + 2*l)*NPIX + row*128 + pxbase + px];
        float v = flows[((size_t)b*26 + 2*l+1)*NPIX + row*128 + pxbase + px];
        s_sx[i] = (float)(pxbase+px) - u;
        s_sy[i] = (float)row - v;
    }
    __syncthreads();
    for(int s=0; s<26; ++s){
        int l = s>>1, cb = (s&1)*32;
        {   // gather A slice: 64 px x 4 chunks, 1 item/thread
            int i = tid;
            int px = i&63, ch = (i>>6)&3;
            float sx = s_sx[l*64+px], sy = s_sy[l*64+px];
            float x0f = floorf(sx), y0f = floorf(sy);
            int x0 = (int)x0f, y0 = (int)y0f;
            float wx1 = sx-x0f, wy1 = sy-y0f, wx0 = 1.f-wx1, wy0 = 1.f-wy1;
            bool vx0 = (unsigned)x0<128u, vx1 = (unsigned)(x0+1)<128u;
            bool vy0 = (unsigned)y0<128u, vy1 = (unsigned)(y0+1)<128u;
            float w00 = (vx0&&vy0)? wx0*wy0 : 0.f;
            float w10 = (vx1&&vy0)? wx1*wy0 : 0.f;
            float w01 = (vx0&&vy1)? wx0*wy1 : 0.f;
            float w11 = (vx1&&vy1)? wx1*wy1 : 0.f;
            int xc0 = max(0,min(127,x0)), xc1 = max(0,min(127,x0+1));
            int yc0 = max(0,min(127,y0)), yc1 = max(0,min(127,y0+1));
            int i00 = yc0*128+xc0, i10 = yc0*128+xc1, i01 = yc1*128+xc0, i11 = yc1*128+xc1;
            const float* hc = hb + (size_t)(cb+ch*8)*NPIX;
            bf16x8 vv;
            #pragma unroll
            for(int e=0;e<8;++e){
                const float* hp8 = hc + (size_t)e*NPIX;
                float val = hp8[i00]*w00 + hp8[i10]*w10 + hp8[i01]*w01 + hp8[i11]*w11;
                vv[e] = f2bf(val);
            }
            *(bf16x8*)&At[px*32 + ch*8] = vv;
        }
        for(int i=tid; i<768; i+=256){     // stage B slice
            int r = i>>2, ch = i&3;
            const float* src = w_ret + (size_t)r*832 + s*32 + ch*8;
            bf16x8 v;
            #pragma unroll
            for(int e=0;e<8;++e) v[e] = f2bf(src[e]);
            *(bf16x8*)&Bt[r*32 + ch*8] = v;
        }
        __syncthreads();
        bf16x8 a = *(const bf16x8*)&At[(wid*16+lr)*32 + lg*8];
        #pragma unroll
        for(int ni=0;ni<12;++ni){
            bf16x8 bb = *(const bf16x8*)&Bt[(ni*16+lr)*32 + lg*8];
            acc[ni] = MFMA(a, bb, acc[ni]);
        }
        __syncthreads();
    }
    // fused GRU: this wave owns px block [wid*16, wid*16+16), all 192 oc in-register
    const float* ib = i2h + (size_t)b*192*NPIX + row*128 + pxbase;
    float* ob = out + (((size_t)b*6 + t)*64)*NPIX + row*128 + pxbase;
    int px4 = wid*16 + lg*4;
    #pragma unroll
    for(int ni=0;ni<4;++ni){
        int oc = ni*16 + lr;
        f32x4 ir = *(const f32x4*)&ib[(size_t)oc*NPIX + px4];
        f32x4 iu = *(const f32x4*)&ib[(size_t)(64+oc)*NPIX + px4];
        f32x4 im = *(const f32x4*)&ib[(size_t)(128+oc)*NPIX + px4];
        f32x4 hp = *(const f32x4*)&hb[(size_t)oc*NPIX + row*128 + pxbase + px4];
        float br = b_ret[oc], bu = b_ret[64+oc], bm = b_ret[128+oc];
        f32x4 st;
        #pragma unroll
        for(int r=0;r<4;++r){
            float hr = acc[ni][r] + br;
            float hu = acc[ni+4][r] + bu;
            float hm = acc[ni+8][r] + bm;
            float rg = sigmf(ir[r] + hr);
            float zg = sigmf(iu[r] + hu);
            float mg = leakyf(im[r] + rg*hm);
            st[r] = zg*hp[r] + (1.f-zg)*mg;
        }
        *(f32x4*)&ob[(size_t)oc*NPIX + px4] = st;
    }
}

extern "C" void kernel_launch(void* const* d_in, const int* in_sizes, int n_in,
                              void* d_out, int out_size, void* d_ws, size_t ws_size,
                              hipStream_t stream) {
    const float* x      = (const float*)d_in[0];
    const float* w_stem = (const float*)d_in[1];
    const float* b_stem = (const float*)d_in[2];
    const float* w_i2h  = (const float*)d_in[3];
    const float* b_i2h  = (const float*)d_in[4];
    const float* w_i2f  = (const float*)d_in[5];
    const float* b_i2f  = (const float*)d_in[6];
    const float* w_h2f  = (const float*)d_in[7];
    const float* b_h2f  = (const float*)d_in[8];
    const float* w_flow = (const float*)d_in[9];
    const float* b_flow = (const float*)d_in[10];
    const float* w_ret  = (const float*)d_in[11];
    const float* b_ret  = (const float*)d_in[12];
    float* out = (float*)d_out;

    float* ws    = (float*)d_ws;
    float* ys    = ws;                                   // 2*384*NPIX
    float* h0    = ys    + (size_t)2 * 384 * NPIX;       // 2*64*NPIX
    float* i2h   = h0    + (size_t)2 * 64  * NPIX;       // 2*192*NPIX
    float* f1    = i2h   + (size_t)2 * 192 * NPIX;       // 2*32*NPIX
    float* flows = f1    + (size_t)2 * 32  * NPIX;       // 2*26*NPIX

    hipMemsetAsync(h0, 0, (size_t)2 * 64 * NPIX * sizeof(float), stream);

    stem_kernel<<<6144, 256, 0, stream>>>(x, w_stem, b_stem, ys);

    for (int t = 0; t < T_; ++t) {
        const float* hprev = (t == 0) ? h0 : out + (size_t)(t - 1) * 64 * NPIX;
        int hstride = (t == 0) ? 64 * NPIX : T_ * 64 * NPIX;
        i2h_mfma<<<1536, 256, 0, stream>>>(ys, t, w_i2h, b_i2h, i2h);
        f1_mfma<<<512, 256, 0, stream>>>(ys, t, hprev, hstride,
                                         w_i2f, b_i2f, w_h2f, b_h2f, f1);
        flow_mfma<<<512, 256, 0, stream>>>(f1, w_flow, b_flow, flows);
        warpret_mfma<<<512, 256, 0, stream>>>(hprev, hstride, flows,
                                              w_ret, b_ret, i2h, out, t);
    }
}

// Round 3
// 916.705 us; speedup vs baseline: 19.8732x; 2.9677x over previous
//
#include <hip/hip_runtime.h>
#include <cstddef>

#define NPIX 16384
#define T_ 6

typedef __attribute__((ext_vector_type(8))) short bf16x8;
typedef __attribute__((ext_vector_type(4))) float f32x4;

__device__ __forceinline__ float leakyf(float x){ return x >= 0.f ? x : 0.2f*x; }
__device__ __forceinline__ float sigmf(float x){ return 1.f/(1.f+__expf(-x)); }
__device__ __forceinline__ short f2bf(float f){
    unsigned u = __float_as_uint(f);
    u += 0x7fffu + ((u>>16)&1u);
    return (short)(u>>16);
}
__device__ __forceinline__ float bf2f(short s){
    return __uint_as_float(((unsigned)(unsigned short)s)<<16);
}
__device__ __forceinline__ f32x4 MFMA(bf16x8 a, bf16x8 b, f32x4 c){
    return __builtin_amdgcn_mfma_f32_16x16x32_bf16(a, b, c, 0, 0, 0);
}

// ---- prep: convert all conv weights to bf16 in [tap][oc][ic] layouts (one contiguous dst) ----
// dst layout: wA_i2h [9][192][64] | wA_f1 [50][32][64] | wA_flow [25][32][32] | wA_ret [26][192][32]
__global__ __launch_bounds__(256) void prep_w(const float* __restrict__ wi2h,
        const float* __restrict__ wf1i, const float* __restrict__ wf1h,
        const float* __restrict__ wfl, const float* __restrict__ wrt,
        short* __restrict__ dst){
    int idx = blockIdx.x*256 + threadIdx.x;
    float v;
    if(idx < 110592){                       // i2h: kk*12288 + oc*64 + ic
        int kk = idx/12288, r = idx%12288, oc = r>>6, ic = r&63;
        v = wi2h[((size_t)(oc*64+ic))*9 + kk];
    } else if(idx < 212992){                // f1: tap*2048 + oc*64 + ic, tap = inp*25+q
        int j = idx-110592; int tap = j>>11, r = j&2047, oc = r>>6, ic = r&63;
        int inp = tap/25, q = tap%25;
        const float* s = inp ? wf1h : wf1i;
        v = s[((size_t)(oc*64+ic))*25 + q];
    } else if(idx < 238592){                // flow: q*1024 + oc*32 + ic (oc padded to 32)
        int j = idx-212992; int q = j>>10, r = j&1023, oc = r>>5, ic = r&31;
        v = (oc < 26) ? wfl[((size_t)(oc*32+ic))*25 + q] : 0.f;
    } else {                                // ret: s*6144 + oc*32 + c
        int j = idx-238592; int s_ = j/6144, r = j%6144, oc = r>>5, c = r&31;
        v = wrt[(size_t)oc*832 + s_*32 + c];
    }
    dst[idx] = f2bf(v);
}

// ---- stem: 3x3 s2 p1 conv -> ys_cl[b][pix][384] bf16 (channels-last), leaky ----
__global__ __launch_bounds__(256) void stem_kernel(const float* __restrict__ x,
        const float* __restrict__ w, const float* __restrict__ bias, short* __restrict__ ys_cl){
    int idx = blockIdx.x*256 + threadIdx.x;
    int pix = idx & 16383;
    int r   = idx >> 14;
    int ocg = r % 48, b = r / 48;
    int oy = pix >> 7, ox = pix & 127;
    int oc0 = ocg*8;
    float xv[54];
    #pragma unroll
    for(int ic=0;ic<6;++ic)
      #pragma unroll
      for(int ky=0;ky<3;++ky){
        int iy = oy*2 - 1 + ky;
        #pragma unroll
        for(int kx=0;kx<3;++kx){
            int ix = ox*2 - 1 + kx;
            bool ok = (unsigned)iy<256u && (unsigned)ix<256u;
            xv[ic*9+ky*3+kx] = ok ? x[((size_t)b*6+ic)*65536 + iy*256 + ix] : 0.f;
        }
      }
    bf16x8 st;
    #pragma unroll
    for(int j=0;j<8;++j){
        int oc = oc0 + j;
        float a = bias[oc];
        const float* wb = w + (size_t)oc*54;
        #pragma unroll
        for(int tap=0;tap<54;++tap) a += xv[tap]*wb[tap];
        st[j] = f2bf(leakyf(a));
    }
    *(bf16x8*)&ys_cl[((size_t)b*NPIX + pix)*384 + oc0] = st;
}

// ---- i2h: 3x3 p1, 64->192, tile 64px x 192oc, K=576 ----
__global__ __launch_bounds__(256) void i2h_mfma(const short* __restrict__ ys_cl, int t,
        const short* __restrict__ wA, const float* __restrict__ bias, float* __restrict__ o){
    __shared__ short xt[100*72];      // halo 10x10, 64ch rows (stride 72)
    __shared__ short wt[192*72];      // per-kk weights [oc][64ch]
    int bx = blockIdx.x;
    int tile = bx & 255, b = bx>>8;
    int ty0 = (tile>>4)*8, tx0 = (tile&15)*8;
    int tid = threadIdx.x, wid = tid>>6, lane = tid&63, lr = lane&15, lg = lane>>4;
    int mw = wid>>1, nw = wid&1;
    f32x4 acc[2][6] = {};
    const short* xbase = ys_cl + (size_t)b*NPIX*384 + t*64;
    for(int i=tid; i<800; i+=256){          // A halo once (both cg)
        int pix = i>>3, c8 = i&7;
        int hy = pix/10, hx = pix - hy*10;
        int py = ty0 - 1 + hy, px = tx0 - 1 + hx;
        bf16x8 v = {};
        if((unsigned)py < 128u && (unsigned)px < 128u)
            v = *(const bf16x8*)&xbase[((size_t)py*128 + px)*384 + c8*8];
        *(bf16x8*)&xt[pix*72 + c8*8] = v;
    }
    for(int kk=0; kk<9; ++kk){
        __syncthreads();
        for(int i=tid; i<1536; i+=256){
            int r = i>>3, c8 = i&7;
            *(bf16x8*)&wt[r*72 + c8*8] = *(const bf16x8*)&wA[((size_t)kk*192 + r)*64 + c8*8];
        }
        __syncthreads();
        int ky = kk/3, kx = kk - ky*3;
        #pragma unroll
        for(int cg=0; cg<2; ++cg){
            bf16x8 av[2], bv[6];
            #pragma unroll
            for(int mi=0;mi<2;++mi){
                int m = mw*32 + mi*16 + lr;
                int hp = ((m>>3)+ky)*10 + (m&7) + kx;
                av[mi] = *(const bf16x8*)&xt[hp*72 + cg*32 + lg*8];
            }
            #pragma unroll
            for(int ni=0;ni<6;++ni){
                int oc = nw*96 + ni*16 + lr;
                bv[ni] = *(const bf16x8*)&wt[oc*72 + cg*32 + lg*8];
            }
            #pragma unroll
            for(int mi=0;mi<2;++mi)
              #pragma unroll
              for(int ni=0;ni<6;++ni)
                acc[mi][ni] = MFMA(av[mi], bv[ni], acc[mi][ni]);
        }
    }
    #pragma unroll
    for(int mi=0;mi<2;++mi){
        int m0 = mw*32 + mi*16 + lg*4;
        int py = ty0 + (m0>>3), px = tx0 + (m0&7);
        #pragma unroll
        for(int ni=0;ni<6;++ni){
            int oc = nw*96 + ni*16 + lr;
            float bvs = bias[oc];
            f32x4 r = acc[mi][ni];
            f32x4 st; st[0]=r[0]+bvs; st[1]=r[1]+bvs; st[2]=r[2]+bvs; st[3]=r[3]+bvs;
            *(f32x4*)&o[((size_t)b*192 + oc)*NPIX + py*128 + px] = st;
        }
    }
}

// ---- f1 = leaky(i2f(x)+h2f(h)): dual 5x5 p2, 64->32, K=3200 -> f1_cl[pix][32] bf16 ----
__global__ __launch_bounds__(256) void f1_mfma(const short* __restrict__ ys_cl, int t,
        const short* __restrict__ h_cl, const short* __restrict__ wA,
        const float* __restrict__ bi, const float* __restrict__ bh,
        short* __restrict__ f1_cl){
    __shared__ short xt[144*72];      // halo 12x12, 64ch rows
    __shared__ short wt[160*72];      // per-ky [kx*32+oc][64ch]
    int bx = blockIdx.x;
    int tile = bx & 255, b = bx>>8;
    int ty0 = (tile>>4)*8, tx0 = (tile&15)*8;
    int tid = threadIdx.x, wid = tid>>6, lane = tid&63, lr = lane&15, lg = lane>>4;
    int mw = wid>>1, nw = wid&1;
    f32x4 acc[2] = {};
    for(int inp=0; inp<2; ++inp){
        const short* xb; int xstride;
        if(inp==0){ xb = ys_cl + (size_t)b*NPIX*384 + t*64; xstride = 384; }
        else      { xb = h_cl  + (size_t)b*NPIX*64;         xstride = 64;  }
        __syncthreads();
        for(int i=tid; i<1152; i+=256){
            int pix = i>>3, c8 = i&7;
            int hy = pix/12, hx = pix - hy*12;
            int py = ty0 - 2 + hy, px = tx0 - 2 + hx;
            bf16x8 v = {};
            if((unsigned)py < 128u && (unsigned)px < 128u)
                v = *(const bf16x8*)&xb[((size_t)py*128 + px)*xstride + c8*8];
            *(bf16x8*)&xt[pix*72 + c8*8] = v;
        }
        for(int ky=0; ky<5; ++ky){
            __syncthreads();
            for(int i=tid; i<1280; i+=256){
                int r = i>>3, c8 = i&7;
                *(bf16x8*)&wt[r*72 + c8*8] =
                    *(const bf16x8*)&wA[((size_t)((inp*25 + ky*5)*32) + r)*64 + c8*8];
            }
            __syncthreads();
            #pragma unroll
            for(int cg=0; cg<2; ++cg)
              #pragma unroll
              for(int kx=0; kx<5; ++kx){
                bf16x8 av[2];
                #pragma unroll
                for(int mi=0;mi<2;++mi){
                    int m = mw*32 + mi*16 + lr;
                    int hp = ((m>>3)+ky)*12 + (m&7) + kx;
                    av[mi] = *(const bf16x8*)&xt[hp*72 + cg*32 + lg*8];
                }
                bf16x8 bb = *(const bf16x8*)&wt[(kx*32 + nw*16 + lr)*72 + cg*32 + lg*8];
                #pragma unroll
                for(int mi=0;mi<2;++mi) acc[mi] = MFMA(av[mi], bb, acc[mi]);
              }
        }
    }
    int j = nw*16 + lr;
    float bvs = bi[j] + bh[j];
    __syncthreads();                       // xt reuse as [64px][40] transpose buffer
    #pragma unroll
    for(int mi=0;mi<2;++mi){
        int m0 = mw*32 + mi*16 + lg*4;
        #pragma unroll
        for(int r=0;r<4;++r) xt[(m0+r)*40 + j] = f2bf(leakyf(acc[mi][r] + bvs));
    }
    __syncthreads();
    {
        int px = tid>>2, c8 = tid&3;       // 64px x 4 chunks = 256
        int pix = (ty0 + (px>>3))*128 + tx0 + (px&7);
        *(bf16x8*)&f1_cl[((size_t)b*NPIX + pix)*32 + c8*8] = *(const bf16x8*)&xt[px*40 + c8*8];
    }
}

// ---- flow: 5x5 p2, 32->26(pad 32), K=800 -> flows f32 NCHW ----
__global__ __launch_bounds__(256) void flow_mfma(const short* __restrict__ f1_cl,
        const short* __restrict__ wA, const float* __restrict__ bias, float* __restrict__ flows){
    __shared__ short xt[144*40];      // halo 12x12, 32ch rows (stride 40)
    __shared__ short wt[160*40];
    int bx = blockIdx.x;
    int tile = bx & 255, b = bx>>8;
    int ty0 = (tile>>4)*8, tx0 = (tile&15)*8;
    int tid = threadIdx.x, wid = tid>>6, lane = tid&63, lr = lane&15, lg = lane>>4;
    int mw = wid>>1, nw = wid&1;
    f32x4 acc[2] = {};
    const short* xb = f1_cl + (size_t)b*NPIX*32;
    for(int i=tid; i<576; i+=256){
        int pix = i>>2, c8 = i&3;
        int hy = pix/12, hx = pix - hy*12;
        int py = ty0 - 2 + hy, px = tx0 - 2 + hx;
        bf16x8 v = {};
        if((unsigned)py < 128u && (unsigned)px < 128u)
            v = *(const bf16x8*)&xb[((size_t)py*128 + px)*32 + c8*8];
        *(bf16x8*)&xt[pix*40 + c8*8] = v;
    }
    for(int ky=0; ky<5; ++ky){
        __syncthreads();
        for(int i=tid; i<640; i+=256){
            int r = i>>2, c4 = i&3;
            *(bf16x8*)&wt[r*40 + c4*8] =
                *(const bf16x8*)&wA[((size_t)(ky*5*32) + r)*32 + c4*8];
        }
        __syncthreads();
        #pragma unroll
        for(int kx=0; kx<5; ++kx){
            bf16x8 av[2];
            #pragma unroll
            for(int mi=0;mi<2;++mi){
                int m = mw*32 + mi*16 + lr;
                int hp = ((m>>3)+ky)*12 + (m&7) + kx;
                av[mi] = *(const bf16x8*)&xt[hp*40 + lg*8];
            }
            bf16x8 bb = *(const bf16x8*)&wt[(kx*32 + nw*16 + lr)*40 + lg*8];
            #pragma unroll
            for(int mi=0;mi<2;++mi) acc[mi] = MFMA(av[mi], bb, acc[mi]);
        }
    }
    int j = nw*16 + lr;
    if(j < 26){
        float bvs = bias[j];
        #pragma unroll
        for(int mi=0;mi<2;++mi){
            int m0 = mw*32 + mi*16 + lg*4;
            int py = ty0 + (m0>>3), px = tx0 + (m0&7);
            f32x4 r = acc[mi];
            f32x4 st; st[0]=r[0]+bvs; st[1]=r[1]+bvs; st[2]=r[2]+bvs; st[3]=r[3]+bvs;
            *(f32x4*)&flows[((size_t)b*26 + j)*NPIX + py*128 + px] = st;
        }
    }
}

// ---- warpret: gather(h_cl bf16) + 64px x 192 x 832 MFMA + fused GRU ----
__global__ __launch_bounds__(256) void warpret_mfma(
        const float* __restrict__ hprev_f32, int hstride,
        const short* __restrict__ h_in,        // h_cl[t] (read)
        const float* __restrict__ flows,
        const short* __restrict__ wret, const float* __restrict__ b_ret,
        const float* __restrict__ ib_f32, float* __restrict__ out,
        short* __restrict__ h_out, int t){
    __shared__ float s_sx[832], s_sy[832];
    __shared__ short At[64*40];
    __shared__ short Bt[192*40];
    __shared__ short Ht[64*72];
    int bx = blockIdx.x;
    int half = bx & 1, row = (bx>>1) & 127, b = bx >> 8;
    int pxbase = half*64;
    int tid = threadIdx.x, wid = tid>>6, lane = tid&63, lr = lane&15, lg = lane>>4;
    const short* hc = h_in + (size_t)b*NPIX*64;
    f32x4 acc[12] = {};
    for(int i=tid; i<832; i+=256){
        int l = i>>6, px = i&63;
        float u = flows[((size_t)b*26 + 2*l)*NPIX + row*128 + pxbase + px];
        float v = flows[((size_t)b*26 + 2*l+1)*NPIX + row*128 + pxbase + px];
        s_sx[i] = (float)(pxbase+px) - u;
        s_sy[i] = (float)row - v;
    }
    __syncthreads();
    for(int s=0; s<26; ++s){
        int l = s>>1, cb = (s&1)*32;
        {   // gather A slice: px=tid&63, ch-chunk=tid>>6
            int px = tid&63, ch = tid>>6;
            float sx = s_sx[l*64+px], sy = s_sy[l*64+px];
            float x0f = floorf(sx), y0f = floorf(sy);
            int x0 = (int)x0f, y0 = (int)y0f;
            float wx1 = sx-x0f, wy1 = sy-y0f, wx0 = 1.f-wx1, wy0 = 1.f-wy1;
            bool vx0 = (unsigned)x0<128u, vx1 = (unsigned)(x0+1)<128u;
            bool vy0 = (unsigned)y0<128u, vy1 = (unsigned)(y0+1)<128u;
            float w00 = (vx0&&vy0)? wx0*wy0 : 0.f;
            float w10 = (vx1&&vy0)? wx1*wy0 : 0.f;
            float w01 = (vx0&&vy1)? wx0*wy1 : 0.f;
            float w11 = (vx1&&vy1)? wx1*wy1 : 0.f;
            int xc0 = max(0,min(127,x0)), xc1 = max(0,min(127,x0+1));
            int yc0 = max(0,min(127,y0)), yc1 = max(0,min(127,y0+1));
            bf16x8 a00 = *(const bf16x8*)&hc[((size_t)yc0*128+xc0)*64 + cb + ch*8];
            bf16x8 a10 = *(const bf16x8*)&hc[((size_t)yc0*128+xc1)*64 + cb + ch*8];
            bf16x8 a01 = *(const bf16x8*)&hc[((size_t)yc1*128+xc0)*64 + cb + ch*8];
            bf16x8 a11 = *(const bf16x8*)&hc[((size_t)yc1*128+xc1)*64 + cb + ch*8];
            bf16x8 rr;
            #pragma unroll
            for(int e=0;e<8;++e)
                rr[e] = f2bf(bf2f(a00[e])*w00 + bf2f(a10[e])*w10 +
                             bf2f(a01[e])*w01 + bf2f(a11[e])*w11);
            *(bf16x8*)&At[px*40 + ch*8] = rr;
        }
        for(int i=tid; i<768; i+=256){
            int r = i>>2, c4 = i&3;
            *(bf16x8*)&Bt[r*40 + c4*8] = *(const bf16x8*)&wret[((size_t)s*192 + r)*32 + c4*8];
        }
        __syncthreads();
        bf16x8 a = *(const bf16x8*)&At[(wid*16+lr)*40 + lg*8];
        #pragma unroll
        for(int ni=0;ni<12;++ni){
            bf16x8 bb = *(const bf16x8*)&Bt[(ni*16+lr)*40 + lg*8];
            acc[ni] = MFMA(a, bb, acc[ni]);
        }
        __syncthreads();
    }
    const float* ib  = ib_f32 + (size_t)b*192*NPIX + row*128 + pxbase;
    const float* hbf = hprev_f32 + (size_t)b*hstride + row*128 + pxbase;
    float* ob = out + (((size_t)b*T_ + t)*64)*NPIX + row*128 + pxbase;
    int px4 = wid*16 + lg*4;
    #pragma unroll
    for(int ni=0;ni<4;++ni){
        int oc = ni*16 + lr;
        f32x4 ir = *(const f32x4*)&ib[(size_t)oc*NPIX + px4];
        f32x4 iu = *(const f32x4*)&ib[(size_t)(64+oc)*NPIX + px4];
        f32x4 im = *(const f32x4*)&ib[(size_t)(128+oc)*NPIX + px4];
        f32x4 hp = *(const f32x4*)&hbf[(size_t)oc*NPIX + px4];
        float br = b_ret[oc], bu = b_ret[64+oc], bm = b_ret[128+oc];
        f32x4 st;
        #pragma unroll
        for(int r=0;r<4;++r){
            float hr = acc[ni][r] + br;
            float hu = acc[ni+4][r] + bu;
            float hm = acc[ni+8][r] + bm;
            float rg = sigmf(ir[r] + hr);
            float zg = sigmf(iu[r] + hu);
            float mg = leakyf(im[r] + rg*hm);
            st[r] = zg*hp[r] + (1.f-zg)*mg;
        }
        *(f32x4*)&ob[(size_t)oc*NPIX + px4] = st;
        #pragma unroll
        for(int r=0;r<4;++r) Ht[(px4+r)*72 + oc] = f2bf(st[r]);
    }
    __syncthreads();
    short* ho = h_out + ((size_t)b*NPIX + row*128 + pxbase)*64;
    for(int i=tid; i<512; i+=256){
        int px = i>>3, c8 = i&7;
        *(bf16x8*)&ho[(size_t)px*64 + c8*8] = *(const bf16x8*)&Ht[px*72 + c8*8];
    }
}

extern "C" void kernel_launch(void* const* d_in, const int* in_sizes, int n_in,
                              void* d_out, int out_size, void* d_ws, size_t ws_size,
                              hipStream_t stream) {
    const float* x      = (const float*)d_in[0];
    const float* w_stem = (const float*)d_in[1];
    const float* b_stem = (const float*)d_in[2];
    const float* w_i2h  = (const float*)d_in[3];
    const float* b_i2h  = (const float*)d_in[4];
    const float* w_i2f  = (const float*)d_in[5];
    const float* b_i2f  = (const float*)d_in[6];
    const float* w_h2f  = (const float*)d_in[7];
    const float* b_h2f  = (const float*)d_in[8];
    const float* w_flow = (const float*)d_in[9];
    const float* b_flow = (const float*)d_in[10];
    const float* w_ret  = (const float*)d_in[11];
    const float* b_ret  = (const float*)d_in[12];
    float* out = (float*)d_out;

    char* w = (char*)d_ws;
    float* h0_f32 = (float*)w;  w += (size_t)2*64*NPIX*4;      // 8.4 MB
    float* i2h    = (float*)w;  w += (size_t)2*192*NPIX*4;     // 25.2 MB
    float* flows  = (float*)w;  w += (size_t)2*26*NPIX*4;      // 3.4 MB
    short* ys_cl  = (short*)w;  w += (size_t)2*NPIX*384*2;     // 25.2 MB
    short* h_clA  = (short*)w;  w += (size_t)2*NPIX*64*2;      // 4.2 MB
    short* h_clB  = (short*)w;  w += (size_t)2*NPIX*64*2;      // 4.2 MB
    short* f1_cl  = (short*)w;  w += (size_t)2*NPIX*32*2;      // 2.1 MB
    short* wAbase = (short*)w;                                 // 0.8 MB
    short* wA_i2h  = wAbase;
    short* wA_f1   = wAbase + 110592;
    short* wA_flow = wAbase + 212992;
    short* wA_ret  = wAbase + 238592;

    prep_w<<<1556, 256, 0, stream>>>(w_i2h, w_i2f, w_h2f, w_flow, w_ret, wAbase);
    hipMemsetAsync(h0_f32, 0, (size_t)2*64*NPIX*4, stream);
    hipMemsetAsync(h_clA, 0, (size_t)2*NPIX*64*2, stream);

    stem_kernel<<<6144, 256, 0, stream>>>(x, w_stem, b_stem, ys_cl);

    for (int t = 0; t < T_; ++t) {
        const float* hprev = (t == 0) ? h0_f32 : out + (size_t)(t - 1) * 64 * NPIX;
        int hstride = (t == 0) ? 64 * NPIX : T_ * 64 * NPIX;
        short* h_in  = (t & 1) ? h_clB : h_clA;
        short* h_nxt = (t & 1) ? h_clA : h_clB;
        i2h_mfma<<<512, 256, 0, stream>>>(ys_cl, t, wA_i2h, b_i2h, i2h);
        f1_mfma<<<512, 256, 0, stream>>>(ys_cl, t, h_in, wA_f1, b_i2f, b_h2f, f1_cl);
        flow_mfma<<<512, 256, 0, stream>>>(f1_cl, wA_flow, b_flow, flows);
        warpret_mfma<<<512, 256, 0, stream>>>(hprev, hstride, h_in, flows,
                                              wA_ret, b_ret, i2h, out, h_nxt, t);
    }
}

// Round 4
// 856.812 us; speedup vs baseline: 21.2623x; 1.0699x over previous
//
#include <hip/hip_runtime.h>
#include <cstddef>

#define NPIX 16384
#define T_ 6

typedef __attribute__((ext_vector_type(8))) short bf16x8;
typedef __attribute__((ext_vector_type(4))) float f32x4;

__device__ __forceinline__ float leakyf(float x){ return x >= 0.f ? x : 0.2f*x; }
__device__ __forceinline__ float sigmf(float x){ return 1.f/(1.f+__expf(-x)); }
__device__ __forceinline__ short f2bf(float f){
    unsigned u = __float_as_uint(f);
    u += 0x7fffu + ((u>>16)&1u);
    return (short)(u>>16);
}
__device__ __forceinline__ float bf2f(short s){
    return __uint_as_float(((unsigned)(unsigned short)s)<<16);
}
__device__ __forceinline__ f32x4 MFMA(bf16x8 a, bf16x8 b, f32x4 c){
    return __builtin_amdgcn_mfma_f32_16x16x32_bf16(a, b, c, 0, 0, 0);
}

// ---- prep: weights -> bf16 [tap][oc][ic] (+ stem im2col [oc][64k]) ----
// wA_i2h [9][192][64] | wA_f1 [50][32][64] | wA_flow [25][32][32] | wA_ret [26][192][32] | wA_stem [384][64]
__global__ __launch_bounds__(256) void prep_w(const float* __restrict__ wi2h,
        const float* __restrict__ wf1i, const float* __restrict__ wf1h,
        const float* __restrict__ wfl, const float* __restrict__ wrt,
        const float* __restrict__ wst, short* __restrict__ dst){
    int idx = blockIdx.x*256 + threadIdx.x;
    float v;
    if(idx < 110592){                       // i2h: kk*12288 + oc*64 + ic
        int kk = idx/12288, r = idx%12288, oc = r>>6, ic = r&63;
        v = wi2h[((size_t)(oc*64+ic))*9 + kk];
    } else if(idx < 212992){                // f1: tap*2048 + oc*64 + ic
        int j = idx-110592; int tap = j>>11, r = j&2047, oc = r>>6, ic = r&63;
        int inp = tap/25, q = tap%25;
        const float* s = inp ? wf1h : wf1i;
        v = s[((size_t)(oc*64+ic))*25 + q];
    } else if(idx < 238592){                // flow: q*1024 + oc*32 + ic (oc pad 32)
        int j = idx-212992; int q = j>>10, r = j&1023, oc = r>>5, ic = r&31;
        v = (oc < 26) ? wfl[((size_t)(oc*32+ic))*25 + q] : 0.f;
    } else if(idx < 398336){                // ret: s*6144 + oc*32 + c
        int j = idx-238592; int s_ = j/6144, r = j%6144, oc = r>>5, c = r&31;
        v = wrt[(size_t)oc*832 + s_*32 + c];
    } else {                                // stem: oc*64 + k, k=ic*9+kk (pad 54->64)
        int j = idx-398336; int oc = j>>6, k = j&63;
        if(k < 54){ int ic = k/9, kk = k%9; v = wst[((size_t)(oc*6+ic))*9 + kk]; }
        else v = 0.f;
    }
    dst[idx] = f2bf(v);
}

// ---- stem MFMA: 3x3 s2 p1, 6->384, K=64(54) -> ys_cl[b][pix][384] bf16, leaky ----
__global__ __launch_bounds__(256) void stem_mfma(const float* __restrict__ x,
        const short* __restrict__ wS, const float* __restrict__ bias, short* __restrict__ ys_cl){
    __shared__ float xh[6*17*18];           // halo [ic][17][18]
    int bx = blockIdx.x;
    int tile = bx & 255, b = bx>>8;
    int ty0 = (tile>>4)*8, tx0 = (tile&15)*8;
    int tid = threadIdx.x, wid = tid>>6, lane = tid&63, lr = lane&15, lg = lane>>4;
    int iy0 = ty0*2-1, ix0 = tx0*2-1;
    for(int i=tid; i<1734; i+=256){
        int ic = i/289, r = i%289, hy = r/17, hx = r%17;
        int iy = iy0+hy, ix = ix0+hx;
        float v = 0.f;
        if((unsigned)iy<256u && (unsigned)ix<256u) v = x[((size_t)b*6+ic)*65536 + iy*256 + ix];
        xh[(ic*17+hy)*18+hx] = v;
    }
    __syncthreads();
    int pxl = wid*16 + lr;                   // A row
    int ry = (pxl>>3)*2, rx = (pxl&7)*2;
    bf16x8 a[2];
    #pragma unroll
    for(int cg=0; cg<2; ++cg){
        #pragma unroll
        for(int e=0; e<8; ++e){
            int k = cg*32 + lg*8 + e;
            float v = 0.f;
            if(k < 54){
                int ic = k/9, t9 = k%9, ky = t9/3, kx = t9%3;
                v = xh[(ic*17 + ry+ky)*18 + rx+kx];
            }
            a[cg][e] = f2bf(v);
        }
    }
    short* yb = ys_cl + (size_t)b*NPIX*384;
    #pragma unroll
    for(int ni=0; ni<24; ++ni){
        int oc = ni*16 + lr;
        f32x4 acc = {};
        #pragma unroll
        for(int cg=0; cg<2; ++cg){
            bf16x8 bb = *(const bf16x8*)&wS[(size_t)oc*64 + cg*32 + lg*8];
            acc = MFMA(a[cg], bb, acc);
        }
        float bvs = bias[oc];
        #pragma unroll
        for(int r=0; r<4; ++r){
            int pxr = wid*16 + lg*4 + r;
            int pix = (ty0 + (pxr>>3))*128 + tx0 + (pxr&7);
            yb[(size_t)pix*384 + oc] = f2bf(leakyf(acc[r]+bvs));
        }
    }
}

// ---- i2h: 3x3 p1, 64->192, tile 64px x 192oc, B direct from global ----
__global__ __launch_bounds__(256) void i2h_mfma(const short* __restrict__ ys_cl, int t,
        const short* __restrict__ wA, const float* __restrict__ bias, float* __restrict__ o){
    __shared__ short xt[100*72];
    int bx = blockIdx.x;
    int tile = bx & 255, b = bx>>8;
    int ty0 = (tile>>4)*8, tx0 = (tile&15)*8;
    int tid = threadIdx.x, wid = tid>>6, lane = tid&63, lr = lane&15, lg = lane>>4;
    int mw = wid>>1, nw = wid&1;
    f32x4 acc[2][6] = {};
    const short* xbase = ys_cl + (size_t)b*NPIX*384 + t*64;
    for(int i=tid; i<800; i+=256){
        int pix = i>>3, c8 = i&7;
        int hy = pix/10, hx = pix - hy*10;
        int py = ty0 - 1 + hy, px = tx0 - 1 + hx;
        bf16x8 v = {};
        if((unsigned)py < 128u && (unsigned)px < 128u)
            v = *(const bf16x8*)&xbase[((size_t)py*128 + px)*384 + c8*8];
        *(bf16x8*)&xt[pix*72 + c8*8] = v;
    }
    __syncthreads();
    for(int kk=0; kk<9; ++kk){
        int ky = kk/3, kx = kk - ky*3;
        #pragma unroll
        for(int cg=0; cg<2; ++cg){
            bf16x8 av[2], bv[6];
            #pragma unroll
            for(int mi=0; mi<2; ++mi){
                int m = mw*32 + mi*16 + lr;
                int hp = ((m>>3)+ky)*10 + (m&7) + kx;
                av[mi] = *(const bf16x8*)&xt[hp*72 + cg*32 + lg*8];
            }
            #pragma unroll
            for(int ni=0; ni<6; ++ni)
                bv[ni] = *(const bf16x8*)&wA[((size_t)kk*192 + nw*96 + ni*16 + lr)*64 + cg*32 + lg*8];
            #pragma unroll
            for(int mi=0; mi<2; ++mi)
              #pragma unroll
              for(int ni=0; ni<6; ++ni)
                acc[mi][ni] = MFMA(av[mi], bv[ni], acc[mi][ni]);
        }
    }
    #pragma unroll
    for(int mi=0; mi<2; ++mi){
        int m0 = mw*32 + mi*16 + lg*4;
        int py = ty0 + (m0>>3), px = tx0 + (m0&7);
        #pragma unroll
        for(int ni=0; ni<6; ++ni){
            int oc = nw*96 + ni*16 + lr;
            float bvs = bias[oc];
            f32x4 r = acc[mi][ni];
            f32x4 st; st[0]=r[0]+bvs; st[1]=r[1]+bvs; st[2]=r[2]+bvs; st[3]=r[3]+bvs;
            *(f32x4*)&o[((size_t)b*192 + oc)*NPIX + py*128 + px] = st;
        }
    }
}

// ---- f1 = leaky(i2f(x)+h2f(h)): dual 5x5 p2, 64->32 -> f1_cl[pix][32] bf16 ----
__global__ __launch_bounds__(256) void f1_mfma(const short* __restrict__ ys_cl, int t,
        const short* __restrict__ h_cl, const short* __restrict__ wA,
        const float* __restrict__ bi, const float* __restrict__ bh,
        short* __restrict__ f1_cl){
    __shared__ short xt[144*72];
    int bx = blockIdx.x;
    int tile = bx & 255, b = bx>>8;
    int ty0 = (tile>>4)*8, tx0 = (tile&15)*8;
    int tid = threadIdx.x, wid = tid>>6, lane = tid&63, lr = lane&15, lg = lane>>4;
    int mw = wid>>1, nw = wid&1;
    f32x4 acc[2] = {};
    for(int inp=0; inp<2; ++inp){
        const short* xb; int xstride;
        if(inp==0){ xb = ys_cl + (size_t)b*NPIX*384 + t*64; xstride = 384; }
        else      { xb = h_cl  + (size_t)b*NPIX*64;         xstride = 64;  }
        __syncthreads();
        for(int i=tid; i<1152; i+=256){
            int pix = i>>3, c8 = i&7;
            int hy = pix/12, hx = pix - hy*12;
            int py = ty0 - 2 + hy, px = tx0 - 2 + hx;
            bf16x8 v = {};
            if((unsigned)py < 128u && (unsigned)px < 128u)
                v = *(const bf16x8*)&xb[((size_t)py*128 + px)*xstride + c8*8];
            *(bf16x8*)&xt[pix*72 + c8*8] = v;
        }
        __syncthreads();
        for(int ky=0; ky<5; ++ky){
            #pragma unroll
            for(int cg=0; cg<2; ++cg)
              #pragma unroll
              for(int kx=0; kx<5; ++kx){
                bf16x8 av[2];
                #pragma unroll
                for(int mi=0; mi<2; ++mi){
                    int m = mw*32 + mi*16 + lr;
                    int hp = ((m>>3)+ky)*12 + (m&7) + kx;
                    av[mi] = *(const bf16x8*)&xt[hp*72 + cg*32 + lg*8];
                }
                bf16x8 bb = *(const bf16x8*)&wA[((size_t)((inp*25 + ky*5 + kx)*32) + nw*16 + lr)*64 + cg*32 + lg*8];
                #pragma unroll
                for(int mi=0; mi<2; ++mi) acc[mi] = MFMA(av[mi], bb, acc[mi]);
              }
        }
    }
    int j = nw*16 + lr;
    float bvs = bi[j] + bh[j];
    __syncthreads();                        // reuse xt as [64px][40] transpose
    #pragma unroll
    for(int mi=0; mi<2; ++mi){
        int m0 = mw*32 + mi*16 + lg*4;
        #pragma unroll
        for(int r=0; r<4; ++r) xt[(m0+r)*40 + j] = f2bf(leakyf(acc[mi][r] + bvs));
    }
    __syncthreads();
    {
        int px = tid>>2, c8 = tid&3;
        int pix = (ty0 + (px>>3))*128 + tx0 + (px&7);
        *(bf16x8*)&f1_cl[((size_t)b*NPIX + pix)*32 + c8*8] = *(const bf16x8*)&xt[px*40 + c8*8];
    }
}

// ---- flow: 5x5 p2, 32->26(pad 32) -> flows f32 NCHW ----
__global__ __launch_bounds__(256) void flow_mfma(const short* __restrict__ f1_cl,
        const short* __restrict__ wA, const float* __restrict__ bias, float* __restrict__ flows){
    __shared__ short xt[144*40];
    int bx = blockIdx.x;
    int tile = bx & 255, b = bx>>8;
    int ty0 = (tile>>4)*8, tx0 = (tile&15)*8;
    int tid = threadIdx.x, wid = tid>>6, lane = tid&63, lr = lane&15, lg = lane>>4;
    int mw = wid>>1, nw = wid&1;
    f32x4 acc[2] = {};
    const short* xb = f1_cl + (size_t)b*NPIX*32;
    for(int i=tid; i<576; i+=256){
        int pix = i>>2, c8 = i&3;
        int hy = pix/12, hx = pix - hy*12;
        int py = ty0 - 2 + hy, px = tx0 - 2 + hx;
        bf16x8 v = {};
        if((unsigned)py < 128u && (unsigned)px < 128u)
            v = *(const bf16x8*)&xb[((size_t)py*128 + px)*32 + c8*8];
        *(bf16x8*)&xt[pix*40 + c8*8] = v;
    }
    __syncthreads();
    for(int ky=0; ky<5; ++ky){
        #pragma unroll
        for(int kx=0; kx<5; ++kx){
            bf16x8 av[2];
            #pragma unroll
            for(int mi=0; mi<2; ++mi){
                int m = mw*32 + mi*16 + lr;
                int hp = ((m>>3)+ky)*12 + (m&7) + kx;
                av[mi] = *(const bf16x8*)&xt[hp*40 + lg*8];
            }
            bf16x8 bb = *(const bf16x8*)&wA[((size_t)((ky*5+kx)*32) + nw*16 + lr)*32 + lg*8];
            #pragma unroll
            for(int mi=0; mi<2; ++mi) acc[mi] = MFMA(av[mi], bb, acc[mi]);
        }
    }
    int j = nw*16 + lr;
    if(j < 26){
        float bvs = bias[j];
        #pragma unroll
        for(int mi=0; mi<2; ++mi){
            int m0 = mw*32 + mi*16 + lg*4;
            int py = ty0 + (m0>>3), px = tx0 + (m0&7);
            f32x4 r = acc[mi];
            f32x4 st; st[0]=r[0]+bvs; st[1]=r[1]+bvs; st[2]=r[2]+bvs; st[3]=r[3]+bvs;
            *(f32x4*)&flows[((size_t)b*26 + j)*NPIX + py*128 + px] = st;
        }
    }
}

// ---- warpret: in-register gather + 64px x 192 x 832 MFMA + fused GRU, sync-free main loop ----
__global__ __launch_bounds__(256) void warpret_mfma(
        const float* __restrict__ hprev_f32, int hstride,
        const short* __restrict__ h_in,
        const float* __restrict__ flows,
        const short* __restrict__ wret, const float* __restrict__ b_ret,
        const float* __restrict__ ib_f32, float* __restrict__ out,
        short* __restrict__ h_out, int t){
    __shared__ float s_sx[832], s_sy[832];
    __shared__ short Ht[64*72];
    int bx = blockIdx.x;
    int half = bx & 1, row = (bx>>1) & 127, b = bx >> 8;
    int pxbase = half*64;
    int tid = threadIdx.x, wid = tid>>6, lane = tid&63, lr = lane&15, lg = lane>>4;
    const short* hc = h_in + (size_t)b*NPIX*64;
    f32x4 acc[12] = {};
    for(int i=tid; i<832; i+=256){
        int l = i>>6, px = i&63;
        float u = flows[((size_t)b*26 + 2*l)*NPIX + row*128 + pxbase + px];
        float v = flows[((size_t)b*26 + 2*l+1)*NPIX + row*128 + pxbase + px];
        s_sx[i] = (float)(pxbase+px) - u;
        s_sy[i] = (float)row - v;
    }
    __syncthreads();
    int mypx = wid*16 + lr;                 // this lane's A row
    for(int l=0; l<13; ++l){
        float sx = s_sx[l*64 + mypx], sy = s_sy[l*64 + mypx];
        float x0f = floorf(sx), y0f = floorf(sy);
        int x0 = (int)x0f, y0 = (int)y0f;
        float wx1 = sx-x0f, wy1 = sy-y0f, wx0 = 1.f-wx1, wy0 = 1.f-wy1;
        bool vx0 = (unsigned)x0<128u, vx1 = (unsigned)(x0+1)<128u;
        bool vy0 = (unsigned)y0<128u, vy1 = (unsigned)(y0+1)<128u;
        float w00 = (vx0&&vy0)? wx0*wy0 : 0.f;
        float w10 = (vx1&&vy0)? wx1*wy0 : 0.f;
        float w01 = (vx0&&vy1)? wx0*wy1 : 0.f;
        float w11 = (vx1&&vy1)? wx1*wy1 : 0.f;
        int xc0 = max(0,min(127,x0)), xc1 = max(0,min(127,x0+1));
        int yc0 = max(0,min(127,y0)), yc1 = max(0,min(127,y0+1));
        #pragma unroll
        for(int cg=0; cg<2; ++cg){
            int cb = cg*32 + lg*8;
            bf16x8 a00 = *(const bf16x8*)&hc[((size_t)yc0*128+xc0)*64 + cb];
            bf16x8 a10 = *(const bf16x8*)&hc[((size_t)yc0*128+xc1)*64 + cb];
            bf16x8 a01 = *(const bf16x8*)&hc[((size_t)yc1*128+xc0)*64 + cb];
            bf16x8 a11 = *(const bf16x8*)&hc[((size_t)yc1*128+xc1)*64 + cb];
            bf16x8 a;
            #pragma unroll
            for(int e=0; e<8; ++e)
                a[e] = f2bf(bf2f(a00[e])*w00 + bf2f(a10[e])*w10 +
                            bf2f(a01[e])*w01 + bf2f(a11[e])*w11);
            int s = l*2 + cg;
            #pragma unroll
            for(int ni=0; ni<12; ++ni){
                bf16x8 bb = *(const bf16x8*)&wret[((size_t)s*192 + ni*16 + lr)*32 + lg*8];
                acc[ni] = MFMA(a, bb, acc[ni]);
            }
        }
    }
    const float* ib  = ib_f32 + (size_t)b*192*NPIX + row*128 + pxbase;
    const float* hbf = hprev_f32 + (size_t)b*hstride + row*128 + pxbase;
    float* ob = out + (((size_t)b*T_ + t)*64)*NPIX + row*128 + pxbase;
    int px4 = wid*16 + lg*4;
    #pragma unroll
    for(int ni=0; ni<4; ++ni){
        int oc = ni*16 + lr;
        f32x4 ir = *(const f32x4*)&ib[(size_t)oc*NPIX + px4];
        f32x4 iu = *(const f32x4*)&ib[(size_t)(64+oc)*NPIX + px4];
        f32x4 im = *(const f32x4*)&ib[(size_t)(128+oc)*NPIX + px4];
        f32x4 hp = *(const f32x4*)&hbf[(size_t)oc*NPIX + px4];
        float br = b_ret[oc], bu = b_ret[64+oc], bm = b_ret[128+oc];
        f32x4 st;
        #pragma unroll
        for(int r=0; r<4; ++r){
            float hr = acc[ni][r] + br;
            float hu = acc[ni+4][r] + bu;
            float hm = acc[ni+8][r] + bm;
            float rg = sigmf(ir[r] + hr);
            float zg = sigmf(iu[r] + hu);
            float mg = leakyf(im[r] + rg*hm);
            st[r] = zg*hp[r] + (1.f-zg)*mg;
        }
        *(f32x4*)&ob[(size_t)oc*NPIX + px4] = st;
        #pragma unroll
        for(int r=0; r<4; ++r) Ht[(px4+r)*72 + oc] = f2bf(st[r]);
    }
    __syncthreads();
    short* ho = h_out + ((size_t)b*NPIX + row*128 + pxbase)*64;
    for(int i=tid; i<512; i+=256){
        int px = i>>3, c8 = i&7;
        *(bf16x8*)&ho[(size_t)px*64 + c8*8] = *(const bf16x8*)&Ht[px*72 + c8*8];
    }
}

extern "C" void kernel_launch(void* const* d_in, const int* in_sizes, int n_in,
                              void* d_out, int out_size, void* d_ws, size_t ws_size,
                              hipStream_t stream) {
    const float* x      = (const float*)d_in[0];
    const float* w_stem = (const float*)d_in[1];
    const float* b_stem = (const float*)d_in[2];
    const float* w_i2h  = (const float*)d_in[3];
    const float* b_i2h  = (const float*)d_in[4];
    const float* w_i2f  = (const float*)d_in[5];
    const float* b_i2f  = (const float*)d_in[6];
    const float* w_h2f  = (const float*)d_in[7];
    const float* b_h2f  = (const float*)d_in[8];
    const float* w_flow = (const float*)d_in[9];
    const float* b_flow = (const float*)d_in[10];
    const float* w_ret  = (const float*)d_in[11];
    const float* b_ret  = (const float*)d_in[12];
    float* out = (float*)d_out;

    char* w = (char*)d_ws;
    float* h0_f32 = (float*)w;  w += (size_t)2*64*NPIX*4;
    float* i2h    = (float*)w;  w += (size_t)2*192*NPIX*4;
    float* flows  = (float*)w;  w += (size_t)2*26*NPIX*4;
    short* ys_cl  = (short*)w;  w += (size_t)2*NPIX*384*2;
    short* h_clA  = (short*)w;  w += (size_t)2*NPIX*64*2;
    short* h_clB  = (short*)w;  w += (size_t)2*NPIX*64*2;
    short* f1_cl  = (short*)w;  w += (size_t)2*NPIX*32*2;
    short* wAbase = (short*)w;
    short* wA_i2h  = wAbase;
    short* wA_f1   = wAbase + 110592;
    short* wA_flow = wAbase + 212992;
    short* wA_ret  = wAbase + 238592;
    short* wA_stem = wAbase + 398336;

    prep_w<<<1652, 256, 0, stream>>>(w_i2h, w_i2f, w_h2f, w_flow, w_ret, w_stem, wAbase);
    hipMemsetAsync(h0_f32, 0, (size_t)2*64*NPIX*4, stream);
    hipMemsetAsync(h_clA, 0, (size_t)2*NPIX*64*2, stream);

    stem_mfma<<<512, 256, 0, stream>>>(x, wA_stem, b_stem, ys_cl);

    for (int t = 0; t < T_; ++t) {
        const float* hprev = (t == 0) ? h0_f32 : out + (size_t)(t - 1) * 64 * NPIX;
        int hstride = (t == 0) ? 64 * NPIX : T_ * 6 * NPIX * 64 / 6;  // = T_*64*NPIX
        hstride = (t == 0) ? 64 * NPIX : T_ * 64 * NPIX;
        short* h_in  = (t & 1) ? h_clB : h_clA;
        short* h_nxt = (t & 1) ? h_clA : h_clB;
        i2h_mfma<<<512, 256, 0, stream>>>(ys_cl, t, wA_i2h, b_i2h, i2h);
        f1_mfma<<<512, 256, 0, stream>>>(ys_cl, t, h_in, wA_f1, b_i2f, b_h2f, f1_cl);
        flow_mfma<<<512, 256, 0, stream>>>(f1_cl, wA_flow, b_flow, flows);
        warpret_mfma<<<512, 256, 0, stream>>>(hprev, hstride, h_in, flows,
                                              wA_ret, b_ret, i2h, out, h_nxt, t);
    }
}